// Round 7
// baseline (897.557 us; speedup 1.0000x reference)
//
#include <hip/hip_runtime.h>

// ---------------------------------------------------------------------------
// TorchGRUClassifier: 2-layer GRU (B=1024, T=256, I=153, H=128) + MLP head.
// Round 10:
//  (1) gio layout -> [t][b] (row = t*1024 + b): per-step data per rec block
//      is one contiguous 12 KB chunk; all per-step loads/stores become
//      imm-offset accesses off ONE pointer (+1 add/step). rec0 counters
//      showed ~60% active-CU VALUBusy, half of it address arithmetic.
//  (2) gi1 projection FUSED into rec0: gi1_{t} = h0_t @ Wih1^T computed with
//      12 extra MFMAs per step on the already-loaded A-fragment, written
//      in place. Kills the gi1_gemm pass (read 67 MB + write 201 MB) and
//      the h0 round-trip.
//  (3) all recurrent weights (Whh0 48, Wih1 48, Whh1 48 regs) homed in AGPRs
//      and consumed directly by inline-asm MFMA ("a" constraint; r7 proved
//      the mechanism). arch ~80 + agpr <=96 ~= 200 < 256 -> no spills,
//      unlike r7's 272.
// ---------------------------------------------------------------------------

typedef __bf16 bf16x8 __attribute__((ext_vector_type(8)));
typedef float  f32x4  __attribute__((ext_vector_type(4)));

#define HS 136   // LDS row stride (bf16): 272 B
#define OS 136   // epilogue output-tile stride
#define AS 168   // gi0 A-tile stride (bf16): conflict-free ds_read_b128

__device__ __forceinline__ f32x4 mfma16(bf16x8 a, bf16x8 b, f32x4 c) {
    return __builtin_amdgcn_mfma_f32_16x16x32_bf16(a, b, c, 0, 0, 0);
}
// MFMA reading the B operand directly from its AGPR home (no copies).
__device__ __forceinline__ void mfma16_agpr(f32x4& acc, bf16x8 a, const bf16x8& b) {
    asm("v_mfma_f32_16x16x32_bf16 %0, %1, %2, %0"
        : "+v"(acc) : "v"(a), "a"(b));
}
__device__ __forceinline__ float sigf(float x) {
    return __builtin_amdgcn_rcpf(1.f + __expf(-x));
}
__device__ __forceinline__ float tanhf_(float x) { return 2.f * sigf(2.f * x) - 1.f; }

// Workgroup barrier WITHOUT the vmcnt(0) drain __syncthreads() emits.
__device__ __forceinline__ void barrier_nodrain() {
    asm volatile("s_waitcnt lgkmcnt(0)" ::: "memory");
    __builtin_amdgcn_s_barrier();
    asm volatile("" ::: "memory");
}

// ---- prep: cast weights to bf16 (W_ih0 padded K 153->160 with zeros) ------
__global__ void prep_w_kernel(const float* __restrict__ Wih0, const float* __restrict__ Whh0,
                              const float* __restrict__ Wih1, const float* __restrict__ Whh1,
                              __bf16* __restrict__ o_ih0, __bf16* __restrict__ o_hh0,
                              __bf16* __restrict__ o_ih1, __bf16* __restrict__ o_hh1) {
    int idx = blockIdx.x * 256 + threadIdx.x;      // grid covers 384*160 = 61440
    if (idx < 384 * 160) {
        int n = idx / 160, k = idx - n * 160;
        o_ih0[idx] = (__bf16)(k < 153 ? Wih0[n * 153 + k] : 0.f);
    }
    if (idx < 384 * 128) {
        o_hh0[idx] = (__bf16)Whh0[idx];
        o_ih1[idx] = (__bf16)Wih1[idx];
        o_hh1[idx] = (__bf16)Whh1[idx];
    }
}

// ---- gi0 GEMM: x[262144,153] @ Wih0^T -> gi0 bf16, layout [t*1024+b][384] --
__global__ __launch_bounds__(512, 2) void gi0_gemm_kernel(
    const float* __restrict__ x, const __bf16* __restrict__ Wih0b,
    __bf16* __restrict__ gi0)
{
    __shared__ __align__(16) __bf16 smem[128 * AS];   // A (42 KB), reused as Os
    const int r0  = blockIdx.x * 128;
    const int tid = threadIdx.x;
    const int w = tid >> 6, lane = tid & 63, q = lane >> 4, c15 = lane & 15;
    const int bb = r0 >> 8;        // batch index (uniform: 128 | 256)
    const int t0 = r0 & 255;       // 0 or 128

    // B fragments first: overlap the x staging below.
    bf16x8 bf[3][5];
    #pragma unroll
    for (int j = 0; j < 3; ++j) {
        int colb = 16 * (w + 8 * j) + c15;
        #pragma unroll
        for (int ks = 0; ks < 5; ++ks)
            bf[j][ks] = *(const bf16x8*)(Wih0b + colb * 160 + ks * 32 + q * 8);
    }

    // staging: panel = 128*153 f32 = 4896 16B chunks, 16B-aligned per block.
    const float* px = x + (size_t)r0 * 153;
    auto scatter = [&](unsigned c, f32x4 v) {
        unsigned m0  = 4u * c;
        unsigned row = m0 / 153u;
        unsigned col = m0 - row * 153u;
        #pragma unroll
        for (int i = 0; i < 4; ++i) {
            unsigned cc = col + i, rr = row;
            if (cc >= 153u) { cc -= 153u; rr += 1u; }
            smem[rr * AS + cc] = (__bf16)v[i];
        }
    };
    #pragma unroll
    for (int p = tid; p < 896; p += 512)
        smem[(p / 7) * AS + 153 + p % 7] = (__bf16)0.f;
    {
        f32x4 v[5];
        #pragma unroll
        for (int k = 0; k < 5; ++k)
            v[k] = *(const f32x4*)(px + 4u * (tid + k * 512));
        #pragma unroll
        for (int k = 0; k < 5; ++k) scatter(tid + k * 512, v[k]);
        f32x4 u[4];
        #pragma unroll
        for (int k = 0; k < 4; ++k)
            u[k] = *(const f32x4*)(px + 4u * (tid + (5 + k) * 512));
        f32x4 tv;
        const bool tail = tid < 288;                 // 4896 = 9*512 + 288
        if (tail) tv = *(const f32x4*)(px + 4u * (tid + 4608));
        #pragma unroll
        for (int k = 0; k < 4; ++k) scatter(tid + (5 + k) * 512, u[k]);
        if (tail) scatter(tid + 4608, tv);
    }
    barrier_nodrain();

    f32x4 acc[8][3];
    #pragma unroll
    for (int rt = 0; rt < 8; ++rt)
        #pragma unroll
        for (int j = 0; j < 3; ++j) acc[rt][j] = (f32x4){0.f, 0.f, 0.f, 0.f};

    #pragma unroll
    for (int ks = 0; ks < 5; ++ks) {
        bf16x8 a[8];
        #pragma unroll
        for (int rt = 0; rt < 8; ++rt)
            a[rt] = *(const bf16x8*)(&smem[(rt * 16 + c15) * AS + ks * 32 + q * 8]);
        #pragma unroll
        for (int rt = 0; rt < 8; ++rt)
            #pragma unroll
            for (int j = 0; j < 3; ++j) acc[rt][j] = mfma16(a[rt], bf[j][ks], acc[rt][j]);
    }
    barrier_nodrain();   // done reading A; reuse as Os
    #pragma unroll
    for (int j = 0; j < 3; ++j) {
        #pragma unroll
        for (int rt = 0; rt < 8; ++rt)
            #pragma unroll
            for (int r = 0; r < 4; ++r)
                smem[(rt * 16 + q * 4 + r) * OS + 16 * w + c15] = (__bf16)acc[rt][j][r];
        barrier_nodrain();
        #pragma unroll
        for (int pass = 0; pass < 4; ++pass) {
            int row = pass * 32 + (tid >> 4);
            int col = (tid & 15) * 8;
            bf16x8 v = *(const bf16x8*)(&smem[row * OS + col]);
            size_t nrow = (size_t)(t0 + row) * 1024 + bb;   // [t][b] layout
            *(bf16x8*)(gi0 + nrow * 384 + j * 128 + col) = v;
        }
        if (j < 2) barrier_nodrain();
    }
}

// ---- rec0 (+fused gi1): layer-0 recurrence; writes gi1 rows in place ------
__global__ __launch_bounds__(512, 2)
void gru_rec0_kernel(__bf16* __restrict__ gio,      // [t][b]: gi0 in, gi1 out
                     const __bf16* __restrict__ Whh0,
                     const __bf16* __restrict__ Wih1b,
                     const float* __restrict__ b_ih0, const float* __restrict__ b_hh0)
{
    __shared__ __align__(16) __bf16 hsA[16 * HS], hsB[16 * HS];

    const int tid  = threadIdx.x;
    const int w    = tid >> 6;
    const int lane = tid & 63;
    const int q    = lane >> 4;
    const int c15  = lane & 15;
    const int c_col = w * 16 + c15;
    const int b0   = blockIdx.x * 16;

    // recurrent + projection weights -> AGPR homes (24 frags = 96 AGPRs)
    bf16x8 fhh[3][4], fih[3][4];
    #pragma unroll
    for (int g = 0; g < 3; ++g)
        #pragma unroll
        for (int ks = 0; ks < 4; ++ks) {
            size_t off = (size_t)(g * 128 + c_col) * 128 + ks * 32 + q * 8;
            fhh[g][ks] = *(const bf16x8*)(Whh0 + off);
            fih[g][ks] = *(const bf16x8*)(Wih1b + off);
        }
    #pragma unroll
    for (int g = 0; g < 3; ++g)
        #pragma unroll
        for (int ks = 0; ks < 4; ++ks) {
            asm volatile("" : "+a"(fhh[g][ks]));
            asm volatile("" : "+a"(fih[g][ks]));
        }

    float Brz[2], bin, bhn;
    Brz[0] = b_ih0[c_col] + b_hh0[c_col];
    Brz[1] = b_ih0[128 + c_col] + b_hh0[128 + c_col];
    bin = b_ih0[256 + c_col]; bhn = b_hh0[256 + c_col];

    float hr[4] = {0.f, 0.f, 0.f, 0.f};
    for (int i = tid; i < 16 * HS; i += 512) { hsA[i] = (__bf16)0.f; hsB[i] = (__bf16)0.f; }
    __syncthreads();

    // [t][b] bases: this thread's 4 rows are b0+q*4+r (r via imm offset)
    const size_t TSTRIDE = (size_t)1024 * 384;
    const __bf16* gp = gio + (size_t)(b0 + q * 4) * 384 + c_col;   // read,  t=0
    __bf16*       wp = gio + (size_t)(b0 + q * 4) * 384 + c_col;   // write, t=0

    __bf16 gvA[4][3], gvB[4][3];
    #pragma unroll
    for (int r = 0; r < 4; ++r)
        #pragma unroll
        for (int g = 0; g < 3; ++g) gvA[r][g] = gp[r * 384 + g * 128];
    gp += TSTRIDE;

    // iteration k: reads h0_{k-1}, computes h0_k; stores gi1_{k-1} (st),
    // prefetches gi0 row t=k+1 (pf, in flight across the nodrain barrier).
    auto body = [&](const __bf16* rd, __bf16* wr,
                    __bf16 (&gR)[4][3], __bf16 (&gW)[4][3],
                    bool pf, bool st) {
        if (pf) {
            #pragma unroll
            for (int r = 0; r < 4; ++r)
                #pragma unroll
                for (int g = 0; g < 3; ++g) gW[r][g] = gp[r * 384 + g * 128];
            gp += TSTRIDE;
        }
        bf16x8 a[4];
        #pragma unroll
        for (int ks = 0; ks < 4; ++ks)
            a[ks] = *(const bf16x8*)(rd + c15 * HS + ks * 32 + q * 8);
        f32x4 hacc[3];
        #pragma unroll
        for (int g = 0; g < 3; ++g) hacc[g] = (f32x4){0.f, 0.f, 0.f, 0.f};
        #pragma unroll
        for (int ks = 0; ks < 4; ++ks)
            #pragma unroll
            for (int g = 0; g < 3; ++g) mfma16_agpr(hacc[g], a[ks], fhh[g][ks]);
        if (st) {   // gi1_{k-1} = h0_{k-1} @ Wih1^T  (same A-fragments)
            f32x4 iacc[3];
            #pragma unroll
            for (int g = 0; g < 3; ++g) iacc[g] = (f32x4){0.f, 0.f, 0.f, 0.f};
            #pragma unroll
            for (int ks = 0; ks < 4; ++ks)
                #pragma unroll
                for (int g = 0; g < 3; ++g) mfma16_agpr(iacc[g], a[ks], fih[g][ks]);
            #pragma unroll
            for (int g = 0; g < 3; ++g)
                #pragma unroll
                for (int r = 0; r < 4; ++r)
                    wp[r * 384 + g * 128] = (__bf16)iacc[g][r];
            wp += TSTRIDE;
        }
        #pragma unroll
        for (int r = 0; r < 4; ++r) {
            float rr = sigf((float)gR[r][0] + hacc[0][r] + Brz[0]);
            float zz = sigf((float)gR[r][1] + hacc[1][r] + Brz[1]);
            float nn = tanhf_((float)gR[r][2] + bin + rr * (hacc[2][r] + bhn));
            float hnew = zz * (hr[r] - nn) + nn;
            hr[r] = hnew;
            wr[(q * 4 + r) * HS + c_col] = (__bf16)hnew;
        }
        barrier_nodrain();
    };

    body(hsA, hsB, gvA, gvB, true, false);            // k = 0
    for (int i = 0; i < 127; ++i) {
        body(hsB, hsA, gvB, gvA, true, true);         // k odd
        body(hsA, hsB, gvA, gvB, true, true);         // k even
    }
    body(hsB, hsA, gvB, gvA, false, true);            // k = 255
    // epilogue: gi1_{255} from h0_255 (in hsA after final barrier)
    {
        bf16x8 a[4];
        #pragma unroll
        for (int ks = 0; ks < 4; ++ks)
            a[ks] = *(const bf16x8*)(hsA + c15 * HS + ks * 32 + q * 8);
        f32x4 iacc[3];
        #pragma unroll
        for (int g = 0; g < 3; ++g) iacc[g] = (f32x4){0.f, 0.f, 0.f, 0.f};
        #pragma unroll
        for (int ks = 0; ks < 4; ++ks)
            #pragma unroll
            for (int g = 0; g < 3; ++g) mfma16_agpr(iacc[g], a[ks], fih[g][ks]);
        #pragma unroll
        for (int g = 0; g < 3; ++g)
            #pragma unroll
            for (int r = 0; r < 4; ++r)
                wp[r * 384 + g * 128] = (__bf16)iacc[g][r];
    }
}

// ---- rec1: layer-1 recurrence + MLP head ([t][b] input) -------------------
__global__ __launch_bounds__(512, 2)
void gru_rec1_kernel(const __bf16* __restrict__ gi1,
                     const __bf16* __restrict__ Whh1,
                     const float* __restrict__ b_ih1, const float* __restrict__ b_hh1,
                     const float* __restrict__ W1, const float* __restrict__ b1,
                     const float* __restrict__ W2, const float* __restrict__ b2,
                     float* __restrict__ out)
{
    __shared__ __align__(16) __bf16 hsA[16 * HS], hsB[16 * HS];
    __shared__ float h1f[16 * 128];
    __shared__ float hdnf[16 * 64];

    const int tid  = threadIdx.x;
    const int w    = tid >> 6;
    const int lane = tid & 63;
    const int q    = lane >> 4;
    const int c15  = lane & 15;
    const int c_col = w * 16 + c15;
    const int b0   = blockIdx.x * 16;

    bf16x8 fhh[3][4];
    #pragma unroll
    for (int g = 0; g < 3; ++g)
        #pragma unroll
        for (int ks = 0; ks < 4; ++ks)
            fhh[g][ks] = *(const bf16x8*)(Whh1 + (size_t)(g * 128 + c_col) * 128 + ks * 32 + q * 8);
    #pragma unroll
    for (int g = 0; g < 3; ++g)
        #pragma unroll
        for (int ks = 0; ks < 4; ++ks)
            asm volatile("" : "+a"(fhh[g][ks]));

    float Brz[2], bin, bhn;
    Brz[0] = b_ih1[c_col] + b_hh1[c_col];
    Brz[1] = b_ih1[128 + c_col] + b_hh1[128 + c_col];
    bin = b_ih1[256 + c_col]; bhn = b_hh1[256 + c_col];

    float hr[4] = {0.f, 0.f, 0.f, 0.f};
    for (int i = tid; i < 16 * HS; i += 512) { hsA[i] = (__bf16)0.f; hsB[i] = (__bf16)0.f; }
    __syncthreads();

    const size_t TSTRIDE = (size_t)1024 * 384;
    const __bf16* gp = gi1 + (size_t)(b0 + q * 4) * 384 + c_col;

    __bf16 gvA[4][3], gvB[4][3];
    #pragma unroll
    for (int r = 0; r < 4; ++r)
        #pragma unroll
        for (int g = 0; g < 3; ++g) gvA[r][g] = gp[r * 384 + g * 128];
    gp += TSTRIDE;

    auto step = [&](const __bf16* rd, __bf16* wr,
                    __bf16 (&gR)[4][3], __bf16 (&gW)[4][3], bool pf) {
        if (pf) {
            #pragma unroll
            for (int r = 0; r < 4; ++r)
                #pragma unroll
                for (int g = 0; g < 3; ++g) gW[r][g] = gp[r * 384 + g * 128];
            gp += TSTRIDE;
        }
        bf16x8 a[4];
        #pragma unroll
        for (int ks = 0; ks < 4; ++ks)
            a[ks] = *(const bf16x8*)(rd + c15 * HS + ks * 32 + q * 8);
        f32x4 hacc[3];
        #pragma unroll
        for (int g = 0; g < 3; ++g) hacc[g] = (f32x4){0.f, 0.f, 0.f, 0.f};
        #pragma unroll
        for (int ks = 0; ks < 4; ++ks)
            #pragma unroll
            for (int g = 0; g < 3; ++g) mfma16_agpr(hacc[g], a[ks], fhh[g][ks]);
        #pragma unroll
        for (int r = 0; r < 4; ++r) {
            float rr = sigf((float)gR[r][0] + hacc[0][r] + Brz[0]);
            float zz = sigf((float)gR[r][1] + hacc[1][r] + Brz[1]);
            float nn = tanhf_((float)gR[r][2] + bin + rr * (hacc[2][r] + bhn));
            float hnew = zz * (hr[r] - nn) + nn;
            hr[r] = hnew;
            wr[(q * 4 + r) * HS + c_col] = (__bf16)hnew;
        }
        barrier_nodrain();
    };

    for (int i = 0; i < 128; ++i) {
        step(hsA, hsB, gvA, gvB, true);        // k = 2i
        step(hsB, hsA, gvB, gvA, i < 127);     // k = 2i+1 (last: no prefetch)
    }

    // ---- head: relu(h1 @ W1^T + b1) @ W2^T + b2 -> sigmoid ----------------
    #pragma unroll
    for (int r = 0; r < 4; ++r) h1f[(q * 4 + r) * 128 + c_col] = hr[r];
    __syncthreads();
    for (int p = tid; p < 16 * 64; p += 512) {
        int m = p >> 6, u = p & 63;
        float s = b1[u];
        const float* hrow = &h1f[m * 128];
        const float* wrow = &W1[u * 128];
        #pragma unroll 8
        for (int k = 0; k < 128; ++k) s += hrow[k] * wrow[k];
        hdnf[p] = fmaxf(s, 0.f);
    }
    __syncthreads();
    if (tid < 16) {
        float s = b2[0];
        #pragma unroll 8
        for (int k = 0; k < 64; ++k) s += hdnf[tid * 64 + k] * W2[k];
        out[b0 + tid] = sigf(s);
    }
}

// ---------------------------------------------------------------------------
extern "C" void kernel_launch(void* const* d_in, const int* in_sizes, int n_in,
                              void* d_out, int out_size, void* d_ws, size_t ws_size,
                              hipStream_t stream) {
    const float* x     = (const float*)d_in[0];
    const float* W_ih0 = (const float*)d_in[1];
    const float* W_hh0 = (const float*)d_in[2];
    const float* bih0  = (const float*)d_in[3];
    const float* bhh0  = (const float*)d_in[4];
    const float* W_ih1 = (const float*)d_in[5];
    const float* W_hh1 = (const float*)d_in[6];
    const float* bih1  = (const float*)d_in[7];
    const float* bhh1  = (const float*)d_in[8];
    const float* W1    = (const float*)d_in[9];
    const float* b1    = (const float*)d_in[10];
    const float* W2    = (const float*)d_in[11];
    const float* b2    = (const float*)d_in[12];
    float* out = (float*)d_out;

    char* ws = (char*)d_ws;
    // ws layout (bytes):
    //   gio   : 262144 x 384 bf16 = 201,326,592  @ 0   ([t][b]: gi0 -> gi1 in place)
    //   Wih0b : 384x160 bf16      =     122,880  @ 201326592
    //   Whh0b / Wih1b / Whh1b : 384x128 bf16 = 98,304 each
    __bf16* gio   = (__bf16*)(ws);
    __bf16* wih0b = (__bf16*)(ws + 201326592);
    __bf16* whh0b = (__bf16*)(ws + 201449472);
    __bf16* wih1b = (__bf16*)(ws + 201547776);
    __bf16* whh1b = (__bf16*)(ws + 201646080);

    prep_w_kernel<<<240, 256, 0, stream>>>(W_ih0, W_hh0, W_ih1, W_hh1,
                                           wih0b, whh0b, wih1b, whh1b);
    gi0_gemm_kernel<<<2048, 512, 0, stream>>>(x, wih0b, gio);
    gru_rec0_kernel<<<64, 512, 0, stream>>>(gio, whh0b, wih1b, bih0, bhh0);
    gru_rec1_kernel<<<64, 512, 0, stream>>>(gio, whh1b, bih1, bhh1,
                                            W1, b1, W2, b2, out);
}

// Round 8
// 705.819 us; speedup vs baseline: 1.2717x; 1.2717x over previous
//
#include <hip/hip_runtime.h>

// ---------------------------------------------------------------------------
// TorchGRUClassifier: 2-layer GRU (B=1024, T=256, I=153, H=128) + MLP head.
// Round 11: FULL 2-layer fusion with minimal HBM traffic.
// Lessons: (r10) AGPR weights + inline-asm MFMA works, zero spills when
// arch+agpr <= 256; (r10) rec kernels pay HBM at small-grid BW (~0.8 TB/s
// @64 CUs) -> bulk traffic belongs in the 2048-block GEMM, NOT the rec.
// Structure: gi0_gemm (unchanged, [t][b]) -> ONE fused rec kernel that
// reads ONLY gi0 (201 MB, the irreducible input) and writes only out[1024].
//   - 36 weight frags (Whh0,Wih1,Whh1) in AGPR (144), consumed by asm MFMA.
//   - gi prefetch single-buffered in 24 regs (reload same regs right after
//     gate use; in flight ~0.7 step across the nodrain barrier).
//   - 128 blocks x 8 batch rows (A-tile half-empty; MFMA has 20x headroom):
//     2x streaming CUs -> HBM floor ~125 us; half the gate rows per thread.
//   - h-tile rows 8..15 stay zero (init once, never written, multiply as 0).
// ---------------------------------------------------------------------------

typedef __bf16 bf16x8 __attribute__((ext_vector_type(8)));
typedef float  f32x4  __attribute__((ext_vector_type(4)));

#define HS 136   // LDS row stride (bf16): 272 B
#define OS 136   // epilogue output-tile stride
#define AS 168   // gi0 A-tile stride (bf16): conflict-free ds_read_b128

__device__ __forceinline__ f32x4 mfma16(bf16x8 a, bf16x8 b, f32x4 c) {
    return __builtin_amdgcn_mfma_f32_16x16x32_bf16(a, b, c, 0, 0, 0);
}
// MFMA reading the B operand directly from its AGPR home (no copies).
__device__ __forceinline__ void mfma16_agpr(f32x4& acc, bf16x8 a, const bf16x8& b) {
    asm("v_mfma_f32_16x16x32_bf16 %0, %1, %2, %0"
        : "+v"(acc) : "v"(a), "a"(b));
}
__device__ __forceinline__ float sigf(float x) {
    return __builtin_amdgcn_rcpf(1.f + __expf(-x));
}
__device__ __forceinline__ float tanhf_(float x) { return 2.f * sigf(2.f * x) - 1.f; }

// Workgroup barrier WITHOUT the vmcnt(0) drain __syncthreads() emits.
__device__ __forceinline__ void barrier_nodrain() {
    asm volatile("s_waitcnt lgkmcnt(0)" ::: "memory");
    __builtin_amdgcn_s_barrier();
    asm volatile("" ::: "memory");
}

// ---- prep: cast weights to bf16 (W_ih0 padded K 153->160 with zeros) ------
__global__ void prep_w_kernel(const float* __restrict__ Wih0, const float* __restrict__ Whh0,
                              const float* __restrict__ Wih1, const float* __restrict__ Whh1,
                              __bf16* __restrict__ o_ih0, __bf16* __restrict__ o_hh0,
                              __bf16* __restrict__ o_ih1, __bf16* __restrict__ o_hh1) {
    int idx = blockIdx.x * 256 + threadIdx.x;      // grid covers 384*160 = 61440
    if (idx < 384 * 160) {
        int n = idx / 160, k = idx - n * 160;
        o_ih0[idx] = (__bf16)(k < 153 ? Wih0[n * 153 + k] : 0.f);
    }
    if (idx < 384 * 128) {
        o_hh0[idx] = (__bf16)Whh0[idx];
        o_ih1[idx] = (__bf16)Wih1[idx];
        o_hh1[idx] = (__bf16)Whh1[idx];
    }
}

// ---- gi0 GEMM: x[262144,153] @ Wih0^T -> gi0 bf16, layout [t*1024+b][384] --
__global__ __launch_bounds__(512, 2) void gi0_gemm_kernel(
    const float* __restrict__ x, const __bf16* __restrict__ Wih0b,
    __bf16* __restrict__ gi0)
{
    __shared__ __align__(16) __bf16 smem[128 * AS];   // A (42 KB), reused as Os
    const int r0  = blockIdx.x * 128;
    const int tid = threadIdx.x;
    const int w = tid >> 6, lane = tid & 63, q = lane >> 4, c15 = lane & 15;
    const int bb = r0 >> 8;        // batch index (uniform: 128 | 256)
    const int t0 = r0 & 255;       // 0 or 128

    // B fragments first: overlap the x staging below.
    bf16x8 bf[3][5];
    #pragma unroll
    for (int j = 0; j < 3; ++j) {
        int colb = 16 * (w + 8 * j) + c15;
        #pragma unroll
        for (int ks = 0; ks < 5; ++ks)
            bf[j][ks] = *(const bf16x8*)(Wih0b + colb * 160 + ks * 32 + q * 8);
    }

    // staging: panel = 128*153 f32 = 4896 16B chunks, 16B-aligned per block.
    const float* px = x + (size_t)r0 * 153;
    auto scatter = [&](unsigned c, f32x4 v) {
        unsigned m0  = 4u * c;
        unsigned row = m0 / 153u;
        unsigned col = m0 - row * 153u;
        #pragma unroll
        for (int i = 0; i < 4; ++i) {
            unsigned cc = col + i, rr = row;
            if (cc >= 153u) { cc -= 153u; rr += 1u; }
            smem[rr * AS + cc] = (__bf16)v[i];
        }
    };
    #pragma unroll
    for (int p = tid; p < 896; p += 512)
        smem[(p / 7) * AS + 153 + p % 7] = (__bf16)0.f;
    {
        f32x4 v[5];
        #pragma unroll
        for (int k = 0; k < 5; ++k)
            v[k] = *(const f32x4*)(px + 4u * (tid + k * 512));
        #pragma unroll
        for (int k = 0; k < 5; ++k) scatter(tid + k * 512, v[k]);
        f32x4 u[4];
        #pragma unroll
        for (int k = 0; k < 4; ++k)
            u[k] = *(const f32x4*)(px + 4u * (tid + (5 + k) * 512));
        f32x4 tv;
        const bool tail = tid < 288;                 // 4896 = 9*512 + 288
        if (tail) tv = *(const f32x4*)(px + 4u * (tid + 4608));
        #pragma unroll
        for (int k = 0; k < 4; ++k) scatter(tid + (5 + k) * 512, u[k]);
        if (tail) scatter(tid + 4608, tv);
    }
    barrier_nodrain();

    f32x4 acc[8][3];
    #pragma unroll
    for (int rt = 0; rt < 8; ++rt)
        #pragma unroll
        for (int j = 0; j < 3; ++j) acc[rt][j] = (f32x4){0.f, 0.f, 0.f, 0.f};

    #pragma unroll
    for (int ks = 0; ks < 5; ++ks) {
        bf16x8 a[8];
        #pragma unroll
        for (int rt = 0; rt < 8; ++rt)
            a[rt] = *(const bf16x8*)(&smem[(rt * 16 + c15) * AS + ks * 32 + q * 8]);
        #pragma unroll
        for (int rt = 0; rt < 8; ++rt)
            #pragma unroll
            for (int j = 0; j < 3; ++j) acc[rt][j] = mfma16(a[rt], bf[j][ks], acc[rt][j]);
    }
    barrier_nodrain();   // done reading A; reuse as Os
    #pragma unroll
    for (int j = 0; j < 3; ++j) {
        #pragma unroll
        for (int rt = 0; rt < 8; ++rt)
            #pragma unroll
            for (int r = 0; r < 4; ++r)
                smem[(rt * 16 + q * 4 + r) * OS + 16 * w + c15] = (__bf16)acc[rt][j][r];
        barrier_nodrain();
        #pragma unroll
        for (int pass = 0; pass < 4; ++pass) {
            int row = pass * 32 + (tid >> 4);
            int col = (tid & 15) * 8;
            bf16x8 v = *(const bf16x8*)(&smem[row * OS + col]);
            size_t nrow = (size_t)(t0 + row) * 1024 + bb;   // [t][b] layout
            *(bf16x8*)(gi0 + nrow * 384 + j * 128 + col) = v;
        }
        if (j < 2) barrier_nodrain();
    }
}

// ---- fused 2-layer recurrence + head; reads ONLY gi0 ----------------------
__global__ __launch_bounds__(512, 2)
void gru_fused_kernel(const __bf16* __restrict__ gi0,   // [t][b]
                      const __bf16* __restrict__ Whh0b, const __bf16* __restrict__ Wih1b,
                      const __bf16* __restrict__ Whh1b,
                      const float* __restrict__ b_ih0, const float* __restrict__ b_hh0,
                      const float* __restrict__ b_ih1, const float* __restrict__ b_hh1,
                      const float* __restrict__ W1, const float* __restrict__ b1,
                      const float* __restrict__ W2, const float* __restrict__ b2,
                      float* __restrict__ out)
{
    __shared__ __align__(16) __bf16 h0sA[16 * HS], h0sB[16 * HS];
    __shared__ __align__(16) __bf16 h1sA[16 * HS], h1sB[16 * HS];
    __shared__ float h1f[8 * 128];
    __shared__ float hdnf[8 * 64];

    const int tid  = threadIdx.x;
    const int w    = tid >> 6;
    const int lane = tid & 63;
    const int q    = lane >> 4;
    const int c15  = lane & 15;
    const int c_col = w * 16 + c15;
    const int b0   = blockIdx.x * 8;          // 128 blocks x 8 batch rows
    const bool gact = (q < 2);                // rows 0..7 live in q=0,1

    // --- 36 weight B-fragments -> AGPR homes (144 AGPRs) -------------------
    bf16x8 fhh0[3][4], fih1[3][4], fhh1[3][4];
    #pragma unroll
    for (int g = 0; g < 3; ++g)
        #pragma unroll
        for (int ks = 0; ks < 4; ++ks) {
            size_t off = (size_t)(g * 128 + c_col) * 128 + ks * 32 + q * 8;
            fhh0[g][ks] = *(const bf16x8*)(Whh0b + off);
            fih1[g][ks] = *(const bf16x8*)(Wih1b + off);
            fhh1[g][ks] = *(const bf16x8*)(Whh1b + off);
        }
    #pragma unroll
    for (int g = 0; g < 3; ++g)
        #pragma unroll
        for (int ks = 0; ks < 4; ++ks) {
            asm volatile("" : "+a"(fhh0[g][ks]));
            asm volatile("" : "+a"(fih1[g][ks]));
            asm volatile("" : "+a"(fhh1[g][ks]));
        }

    float B0rz[2], B1rz[2], bi0n, bh0n, bi1n, bh1n;
    B0rz[0] = b_ih0[c_col] + b_hh0[c_col];
    B0rz[1] = b_ih0[128 + c_col] + b_hh0[128 + c_col];
    B1rz[0] = b_ih1[c_col] + b_hh1[c_col];
    B1rz[1] = b_ih1[128 + c_col] + b_hh1[128 + c_col];
    bi0n = b_ih0[256 + c_col]; bh0n = b_hh0[256 + c_col];
    bi1n = b_ih1[256 + c_col]; bh1n = b_hh1[256 + c_col];

    float h0r[4] = {0.f, 0.f, 0.f, 0.f};
    float h1r[4] = {0.f, 0.f, 0.f, 0.f};
    for (int i = tid; i < 16 * HS; i += 512) {
        h0sA[i] = (__bf16)0.f; h0sB[i] = (__bf16)0.f;
        h1sA[i] = (__bf16)0.f; h1sB[i] = (__bf16)0.f;   // rows 8..15 stay 0
    }
    __syncthreads();

    // gi0 [t][b]: this thread's 4 rows = b0 + q*4 + r (valid for q<2).
    const size_t TS = (size_t)1024 * 384;
    const __bf16* gp = gi0 + (size_t)(b0 + q * 4) * 384 + c_col;

    // single-buffered gi regs: reloaded right after gate consumption
    __bf16 gv[4][3];
    if (gact) {
        #pragma unroll
        for (int r = 0; r < 4; ++r)
            #pragma unroll
            for (int g = 0; g < 3; ++g) gv[r][g] = gp[r * 384 + g * 128];
        gp += TS;
    }

    auto step = [&](const __bf16* h0rd, __bf16* h0wr,
                    const __bf16* h1rd, __bf16* h1wr, bool reload) {
        // layer0: gh0 = h0 @ Whh0^T
        bf16x8 a[4];
        #pragma unroll
        for (int ks = 0; ks < 4; ++ks)
            a[ks] = *(const bf16x8*)(h0rd + c15 * HS + ks * 32 + q * 8);
        f32x4 hacc[3];
        #pragma unroll
        for (int g = 0; g < 3; ++g) hacc[g] = (f32x4){0.f, 0.f, 0.f, 0.f};
        #pragma unroll
        for (int ks = 0; ks < 4; ++ks)
            #pragma unroll
            for (int g = 0; g < 3; ++g) mfma16_agpr(hacc[g], a[ks], fhh0[g][ks]);
        if (gact) {
            #pragma unroll
            for (int r = 0; r < 4; ++r) {
                float rr = sigf((float)gv[r][0] + hacc[0][r] + B0rz[0]);
                float zz = sigf((float)gv[r][1] + hacc[1][r] + B0rz[1]);
                float nn = tanhf_((float)gv[r][2] + bi0n + rr * (hacc[2][r] + bh0n));
                float hnew = zz * (h0r[r] - nn) + nn;
                h0r[r] = hnew;
                h0wr[(q * 4 + r) * HS + c_col] = (__bf16)hnew;
            }
            if (reload) {   // refill same regs; in flight across the barrier
                #pragma unroll
                for (int r = 0; r < 4; ++r)
                    #pragma unroll
                    for (int g = 0; g < 3; ++g) gv[r][g] = gp[r * 384 + g * 128];
                gp += TS;
            }
        }
        barrier_nodrain();   // the ONLY barrier per step (no vmcnt drain)
        // layer1: gi1 = h0_new @ Wih1^T ; gh1 = h1 @ Whh1^T
        f32x4 iacc[3], hacc1[3];
        #pragma unroll
        for (int g = 0; g < 3; ++g) {
            iacc[g]  = (f32x4){0.f, 0.f, 0.f, 0.f};
            hacc1[g] = (f32x4){0.f, 0.f, 0.f, 0.f};
        }
        #pragma unroll
        for (int ks = 0; ks < 4; ++ks) {
            bf16x8 a0 = *(const bf16x8*)(h0wr + c15 * HS + ks * 32 + q * 8);
            bf16x8 a1 = *(const bf16x8*)(h1rd + c15 * HS + ks * 32 + q * 8);
            #pragma unroll
            for (int g = 0; g < 3; ++g) {
                mfma16_agpr(iacc[g],  a0, fih1[g][ks]);
                mfma16_agpr(hacc1[g], a1, fhh1[g][ks]);
            }
        }
        if (gact) {
            #pragma unroll
            for (int r = 0; r < 4; ++r) {
                float rr = sigf(iacc[0][r] + hacc1[0][r] + B1rz[0]);
                float zz = sigf(iacc[1][r] + hacc1[1][r] + B1rz[1]);
                float nn = tanhf_(iacc[2][r] + bi1n + rr * (hacc1[2][r] + bh1n));
                float hnew = zz * (h1r[r] - nn) + nn;
                h1r[r] = hnew;
                h1wr[(q * 4 + r) * HS + c_col] = (__bf16)hnew;
            }
        }
    };

    for (int i = 0; i < 128; ++i) {
        step(h0sA, h0sB, h1sA, h1sB, true);       // t = 2i
        step(h0sB, h0sA, h1sB, h1sA, i < 127);    // t = 2i+1 (t=255: no reload)
    }

    // ---- head: relu(h1 @ W1^T + b1) @ W2^T + b2 -> sigmoid ----------------
    if (gact) {
        #pragma unroll
        for (int r = 0; r < 4; ++r) h1f[(q * 4 + r) * 128 + c_col] = h1r[r];
    }
    __syncthreads();
    {
        int p = tid;                      // 8*64 = 512 = blockDim
        int m = p >> 6, u = p & 63;
        float s = b1[u];
        const float* hrow = &h1f[m * 128];
        const float* wrow = &W1[u * 128];
        #pragma unroll 8
        for (int k = 0; k < 128; ++k) s += hrow[k] * wrow[k];
        hdnf[p] = fmaxf(s, 0.f);
    }
    __syncthreads();
    if (tid < 8) {
        float s = b2[0];
        #pragma unroll 8
        for (int k = 0; k < 64; ++k) s += hdnf[tid * 64 + k] * W2[k];
        out[b0 + tid] = sigf(s);
    }
}

// ---------------------------------------------------------------------------
extern "C" void kernel_launch(void* const* d_in, const int* in_sizes, int n_in,
                              void* d_out, int out_size, void* d_ws, size_t ws_size,
                              hipStream_t stream) {
    const float* x     = (const float*)d_in[0];
    const float* W_ih0 = (const float*)d_in[1];
    const float* W_hh0 = (const float*)d_in[2];
    const float* bih0  = (const float*)d_in[3];
    const float* bhh0  = (const float*)d_in[4];
    const float* W_ih1 = (const float*)d_in[5];
    const float* W_hh1 = (const float*)d_in[6];
    const float* bih1  = (const float*)d_in[7];
    const float* bhh1  = (const float*)d_in[8];
    const float* W1    = (const float*)d_in[9];
    const float* b1    = (const float*)d_in[10];
    const float* W2    = (const float*)d_in[11];
    const float* b2    = (const float*)d_in[12];
    float* out = (float*)d_out;

    char* ws = (char*)d_ws;
    // ws layout (bytes):
    //   gi0   : 262144 x 384 bf16 = 201,326,592  @ 0   ([t][b] layout)
    //   Wih0b : 384x160 bf16      =     122,880  @ 201326592
    //   Whh0b / Wih1b / Whh1b : 384x128 bf16 = 98,304 each
    __bf16* gi0   = (__bf16*)(ws);
    __bf16* wih0b = (__bf16*)(ws + 201326592);
    __bf16* whh0b = (__bf16*)(ws + 201449472);
    __bf16* wih1b = (__bf16*)(ws + 201547776);
    __bf16* whh1b = (__bf16*)(ws + 201646080);

    prep_w_kernel<<<240, 256, 0, stream>>>(W_ih0, W_hh0, W_ih1, W_hh1,
                                           wih0b, whh0b, wih1b, whh1b);
    gi0_gemm_kernel<<<2048, 512, 0, stream>>>(x, wih0b, gi0);
    gru_fused_kernel<<<128, 512, 0, stream>>>(gi0, whh0b, wih1b, whh1b,
                                              bih0, bhh0, bih1, bhh1,
                                              W1, b1, W2, b2, out);
}